// Round 1
// baseline (714.909 us; speedup 1.0000x reference)
//
#include <hip/hip_runtime.h>
#include <math.h>

#define FLAT   8192
#define NB     64
#define NN     128
#define HD     128
#define NODES_ 64
#define NODEV_ 32
#define OUTS_  32
#define OUTV_  16
#define RBF_   16
#define ZEMB_  32
#define HID_   128
#define LAT_   256
#define NE_    512
#define EATT_  4096
#define WN_    4608
#define ND_    160
#define OD_    80
#define MAXACT 4096

__device__ __forceinline__ float silu_f(float x) { return x / (1.f + __expf(-x)); }
__device__ __forceinline__ float sigm_f(float x) { return 1.f / (1.f + __expf(-x)); }

// ---------------- init: zero accumulators, widx = -1, count = 0 ----------------
__global__ void k_init(float* acc, float* vabs, int* widx, int* count) {
  int t = blockIdx.x * 256 + threadIdx.x;
  if (t < MAXACT * 96) acc[t] = 0.f;
  if (t < NB * OD_) vabs[t] = 0.f;
  if (t < FLAT) widx[t] = -1;
  if (t == 0) *count = 0;
}

// ---------------- scatter: last-write-wins == max edge index ----------------
__global__ void k_scatter(const int* __restrict__ att_dst, int* widx) {
  int i = blockIdx.x * 256 + threadIdx.x;
  if (i < EATT_) atomicMax(&widx[att_dst[i]], i);
}

// ---------------- build compact active-node list ----------------
__global__ void k_build(const int* __restrict__ widx, int* active, int* count) {
  int j = blockIdx.x * 256 + threadIdx.x;
  if (j < FLAT && widx[j] >= 0) {
    int p = atomicAdd(count, 1);
    active[p] = j;
  }
}

// ---------------- per active node: rbf, hidden a(128), gate, env, coefs ----------------
__global__ void k_node(const int* __restrict__ count, const int* __restrict__ active,
                       const int* __restrict__ widx,
                       const float* __restrict__ att_dist, const float* __restrict__ att_vec,
                       const int* __restrict__ z, const float* __restrict__ w_zemb,
                       const int* __restrict__ abs_idx,
                       const float* __restrict__ w1_rad, const float* __restrict__ b1_rad,
                       const float* __restrict__ h,
                       const float* __restrict__ wg1, const float* __restrict__ bg1,
                       const float* __restrict__ wg2, const float* __restrict__ bg2,
                       const float* __restrict__ h_full,
                       float* a_glob, float* coef_glob, float* meta_f, int* meta_b) {
  int pos = blockIdx.x;
  if (pos >= *count) return;
  int t = threadIdx.x;  // 128 threads
  __shared__ float win[49];
  __shared__ float yv_s[3];
  __shared__ float red[128];
  __shared__ float sh_d;

  int j = active[pos];
  int b = j >> 7;
  int n = j & 127;
  int e = widx[j];

  if (t == 0) {
    float d = att_dist[e];
    sh_d = d;
    float eps = fmaxf(d, 1e-8f);
    const float s3 = 1.7320508075688772f;
    yv_s[0] = s3 * att_vec[e * 3 + 0] / eps;
    yv_s[1] = s3 * att_vec[e * 3 + 1] / eps;
    yv_s[2] = s3 * att_vec[e * 3 + 2] / eps;
  }
  int nabs = abs_idx[b];
  float isab = (n == nabs) ? 1.f : 0.f;
  if (t < 32) win[t] = w_zemb[z[j] * 32 + t];
  if (t == 32) win[32] = isab;
  if (t >= 33 && t < 49) {
    int k = t - 33;
    float d = att_dist[e];
    float x = (d - (float)k * (1.f / 3.f)) * 3.f;  // width = 1/3
    win[t] = __expf(-0.5f * x * x);
  }
  __syncthreads();

  // hidden a = silu(win @ w1_rad + b1_rad)   (49 -> 128)
  {
    float s = b1_rad[t];
    for (int k = 0; k < 49; ++k) s = fmaf(win[k], w1_rad[k * 128 + t], s);
    a_glob[pos * 128 + t] = silu_f(s);
  }

  // gate MLP hidden (273 -> 128)
  {
    float g = bg1[t];
    const float* habs = h + (size_t)(b * 128 + nabs) * 128;
    const float* hn   = h + (size_t)j * 128;
    for (int c = 0; c < 128; ++c) g = fmaf(habs[c], wg1[c * 128 + t], g);
    for (int c = 0; c < 128; ++c) g = fmaf(hn[c],   wg1[(128 + c) * 128 + t], g);
    for (int k = 0; k < 16; ++k)  g = fmaf(win[33 + k], wg1[(256 + k) * 128 + t], g);
    g = fmaf(isab, wg1[272 * 128 + t], g);
    red[t] = silu_f(g) * wg2[t];
  }
  __syncthreads();

  // per-node contraction coefficients: [s1(64), p*inv_s3(32), v1(96)]
  const float* hf = h_full + (size_t)j * 160;
  if (t < 64) coef_glob[pos * 192 + t] = hf[t];
  if (t >= 64 && t < 96) {
    int i = t - 64;
    float pv = hf[64 + i * 3 + 0] * yv_s[0] + hf[64 + i * 3 + 1] * yv_s[1] +
               hf[64 + i * 3 + 2] * yv_s[2];
    coef_glob[pos * 192 + t] = pv * 0.5773502691896258f;  // * 1/sqrt(3)
  }
  if (t < 96) coef_glob[pos * 192 + 96 + t] = hf[64 + t];

  if (t == 0) {
    float tot = 0.f;
    for (int k = 0; k < 128; ++k) tot += red[k];
    tot += bg2[0];
    float gate = sigm_f(tot);
    float d = sh_d;
    float env = (d < 5.f) ? 0.5f * (__cosf(3.14159265358979323846f * d * 0.2f) + 1.f) : 0.f;
    meta_f[pos * 4 + 0] = yv_s[0];
    meta_f[pos * 4 + 1] = yv_s[1];
    meta_f[pos * 4 + 2] = yv_s[2];
    meta_f[pos * 4 + 3] = gate * env;
    meta_b[pos] = b;
  }
}

// ---------------- radial GEMM + fused contraction ----------------
// grid (18 col-tiles x 64 node-tiles); each col-tile of 256 cols lies in one of
// the A/B/C/D regions of w2_rad (128 x 4608). tpw[node][col] = a[node].w2[:,col]+b2
// is contracted on the fly into 96 accumulator slots per node.
__global__ __launch_bounds__(256, 2) void k_rgemm(const int* __restrict__ count,
                                                  const float* __restrict__ a_glob,
                                                  const float* __restrict__ coef_glob,
                                                  const float* __restrict__ w2,
                                                  const float* __restrict__ b2,
                                                  float* acc_glob) {
  int tile = blockIdx.x;   // 0..17
  int nbase = blockIdx.y * 64;
  int cnt = *count;
  if (nbase >= cnt) return;
  int nn = min(64, cnt - nbase);
  int t = threadIdx.x;

  __shared__ float a_lds[64 * 128];   // 32 KB
  __shared__ float coef_lds[64 * 48]; // up to 12 KB used
  __shared__ float acc_lds[64 * 48];  // up to 12 KB used

  // region decode (uniform per block)
  int i_loc, o, CW, nslots, slotbase, coefbase;
  if (tile < 8)       { i_loc = t >> 5; o = t & 31; CW = 8;  nslots = 32; slotbase = 0;  coefbase = tile * 8; }
  else if (tile < 12) { i_loc = t >> 5; o = t & 31; CW = 8;  nslots = 32; slotbase = 0;  coefbase = 64 + (tile - 8) * 8; }
  else if (tile < 16) { i_loc = t >> 4; o = t & 15; CW = 16; nslots = 16; slotbase = 32; coefbase = (tile - 12) * 16; }
  else                { i_loc = t >> 4; o = t & 15; CW = 48; nslots = 48; slotbase = 48; coefbase = 96 + (tile - 16) * 48; }
  bool isD = (tile >= 16);

  // stage a (vectorized) and coef slice; zero acc
  {
    const float4* ag = (const float4*)(a_glob + (size_t)nbase * 128);
    float4* al4 = (float4*)a_lds;
    for (int idx = t; idx < nn * 32; idx += 256) al4[idx] = ag[idx];
    for (int idx = t; idx < nn * CW; idx += 256) {
      int r = idx / CW, cc = idx - r * CW;
      coef_lds[idx] = coef_glob[(size_t)(nbase + r) * 192 + coefbase + cc];
    }
    for (int idx = t; idx < nn * nslots; idx += 256) acc_lds[idx] = 0.f;
  }
  __syncthreads();

  int col = tile * 256 + t;
  float b2c = b2[col];
  const float* w2c = w2 + col;

  for (int r0 = 0; r0 < nn; r0 += 4) {
    float s0 = 0.f, s1 = 0.f, s2 = 0.f, s3 = 0.f;
    const float* a0 = a_lds + (r0 + 0) * 128;
    const float* a1 = a_lds + (r0 + 1) * 128;
    const float* a2 = a_lds + (r0 + 2) * 128;
    const float* a3 = a_lds + (r0 + 3) * 128;
#pragma unroll 8
    for (int hh = 0; hh < 128; ++hh) {
      float w = w2c[hh * 4608];
      s0 = fmaf(a0[hh], w, s0);
      s1 = fmaf(a1[hh], w, s1);
      s2 = fmaf(a2[hh], w, s2);
      s3 = fmaf(a3[hh], w, s3);
    }
    float tp[4] = {s0 + b2c, s1 + b2c, s2 + b2c, s3 + b2c};
    int rmax = min(4, nn - r0);
    for (int rr = 0; rr < rmax; ++rr) {
      int r = r0 + rr;
      float tpw = tp[rr];
      if (!isD) {
        atomicAdd(&acc_lds[r * nslots + o], tpw * coef_lds[r * CW + i_loc]);
      } else {
        atomicAdd(&acc_lds[r * 48 + o * 3 + 0], tpw * coef_lds[r * 48 + i_loc * 3 + 0]);
        atomicAdd(&acc_lds[r * 48 + o * 3 + 1], tpw * coef_lds[r * 48 + i_loc * 3 + 1]);
        atomicAdd(&acc_lds[r * 48 + o * 3 + 2], tpw * coef_lds[r * 48 + i_loc * 3 + 2]);
      }
    }
  }
  __syncthreads();
  for (int idx = t; idx < nn * nslots; idx += 256) {
    int r = idx / nslots, s = idx - r * nslots;
    atomicAdd(&acc_glob[(size_t)(nbase + r) * 96 + slotbase + s], acc_lds[idx]);
  }
}

// ---------------- combine per-node accumulators into v_abs[b][80] ----------------
__global__ void k_combine(const int* __restrict__ count, const float* __restrict__ acc_glob,
                          const float* __restrict__ meta_f, const int* __restrict__ meta_b,
                          float* vabs) {
  int pos = blockIdx.x * 256 + threadIdx.x;
  if (pos >= *count) return;
  const float* acc = acc_glob + (size_t)pos * 96;
  float yv0 = meta_f[pos * 4 + 0], yv1 = meta_f[pos * 4 + 1], yv2 = meta_f[pos * 4 + 2];
  float ge = meta_f[pos * 4 + 3];
  const float norm = 0.10206207261596577f;  // 1/sqrt(96)
  float sc = norm * ge;
  float* vb = vabs + meta_b[pos] * 80;
  for (int o = 0; o < 32; ++o) atomicAdd(&vb[o], acc[o] * sc);
  for (int o = 0; o < 16; ++o) {
    float q = acc[32 + o];
    atomicAdd(&vb[32 + o * 3 + 0], (q * yv0 + acc[48 + o * 3 + 0]) * sc);
    atomicAdd(&vb[32 + o * 3 + 1], (q * yv1 + acc[48 + o * 3 + 1]) * sc);
    atomicAdd(&vb[32 + o * 3 + 2], (q * yv2 + acc[48 + o * 3 + 2]) * sc);
  }
}

// ---------------- edge-feature scales -> scale_full[512][80] ----------------
__global__ void k_scales(const float* __restrict__ e_feat,
                         const float* __restrict__ we1, const float* __restrict__ be1,
                         const float* __restrict__ we2, const float* __restrict__ be2,
                         float* sfull) {
  int row = blockIdx.x;  // 512
  int t = threadIdx.x;   // 128
  __shared__ float hid[128];
  const float* ef = e_feat + row * 16;
  float s = be1[t];
  for (int k = 0; k < 16; ++k) s = fmaf(ef[k], we1[k * 128 + t], s);
  hid[t] = silu_f(s);
  __syncthreads();
  if (t < 48) {
    float o = be2[t];
    for (int k = 0; k < 128; ++k) o = fmaf(hid[k], we2[k * 48 + t], o);
    if (t < 32) sfull[row * 80 + t] = o;
    else {
      int oo = t - 32;
      sfull[row * 80 + 32 + oo * 3 + 0] = o;
      sfull[row * 80 + 32 + oo * 3 + 1] = o;
      sfull[row * 80 + 32 + oo * 3 + 2] = o;
    }
  }
}

// ---------------- head MLP: 32 rows/block, 48->128->128->256 ----------------
__global__ void k_head(const float* __restrict__ vabs, const float* __restrict__ sfull,
                       const float* __restrict__ wo1, const float* __restrict__ bo1,
                       const float* __restrict__ wo2, const float* __restrict__ bo2,
                       const float* __restrict__ wo3, const float* __restrict__ bo3,
                       float* __restrict__ out) {
  int blk = blockIdx.x;     // 1024 = 64 b x 16 e-tiles
  int b = blk >> 4;
  int e0 = (blk & 15) * 32;
  int t = threadIdx.x;      // 256

  __shared__ float va[80];
  __shared__ float sfl[32 * 80];
  __shared__ float inv[32 * 48];
  __shared__ float x1[32 * 128];
  __shared__ float x2[32 * 128];

  if (t < 80) va[t] = vabs[b * 80 + t];
  for (int idx = t; idx < 32 * 80; idx += 256) sfl[idx] = sfull[e0 * 80 + idx];
  __syncthreads();

  for (int idx = t; idx < 32 * 48; idx += 256) {
    int r = idx / 48, c = idx - r * 48;
    float v;
    if (c < 32) v = va[c] * sfl[r * 80 + c];
    else {
      int base = 32 + (c - 32) * 3;
      float m0 = va[base + 0] * sfl[r * 80 + base + 0];
      float m1 = va[base + 1] * sfl[r * 80 + base + 1];
      float m2 = va[base + 2] * sfl[r * 80 + base + 2];
      v = sqrtf(m0 * m0 + m1 * m1 + m2 * m2 + 1e-12f);
    }
    inv[idx] = v;
  }
  __syncthreads();

  // layer 1: inv(32x48) @ wo1(48x128) -> silu -> x1
  {
    int col = t & 127, rg = t >> 7;
    float bb = bo1[col];
    for (int r0 = rg * 16; r0 < rg * 16 + 16; r0 += 4) {
      float a0 = bb, a1 = bb, a2 = bb, a3 = bb;
#pragma unroll 8
      for (int k = 0; k < 48; ++k) {
        float w = wo1[k * 128 + col];
        a0 = fmaf(inv[(r0 + 0) * 48 + k], w, a0);
        a1 = fmaf(inv[(r0 + 1) * 48 + k], w, a1);
        a2 = fmaf(inv[(r0 + 2) * 48 + k], w, a2);
        a3 = fmaf(inv[(r0 + 3) * 48 + k], w, a3);
      }
      x1[(r0 + 0) * 128 + col] = silu_f(a0);
      x1[(r0 + 1) * 128 + col] = silu_f(a1);
      x1[(r0 + 2) * 128 + col] = silu_f(a2);
      x1[(r0 + 3) * 128 + col] = silu_f(a3);
    }
  }
  __syncthreads();

  // layer 2: x1(32x128) @ wo2(128x128) -> silu -> x2
  {
    int col = t & 127, rg = t >> 7;
    float bb = bo2[col];
    for (int r0 = rg * 16; r0 < rg * 16 + 16; r0 += 4) {
      float a0 = bb, a1 = bb, a2 = bb, a3 = bb;
#pragma unroll 8
      for (int k = 0; k < 128; ++k) {
        float w = wo2[k * 128 + col];
        a0 = fmaf(x1[(r0 + 0) * 128 + k], w, a0);
        a1 = fmaf(x1[(r0 + 1) * 128 + k], w, a1);
        a2 = fmaf(x1[(r0 + 2) * 128 + k], w, a2);
        a3 = fmaf(x1[(r0 + 3) * 128 + k], w, a3);
      }
      x2[(r0 + 0) * 128 + col] = silu_f(a0);
      x2[(r0 + 1) * 128 + col] = silu_f(a1);
      x2[(r0 + 2) * 128 + col] = silu_f(a2);
      x2[(r0 + 3) * 128 + col] = silu_f(a3);
    }
  }
  __syncthreads();

  // layer 3: x2(32x128) @ wo3(128x256) + bo3 -> out
  {
    int col = t;  // 0..255
    float bb = bo3[col];
    float* op = out + ((size_t)(b * 512 + e0)) * 256 + col;
    for (int r0 = 0; r0 < 32; r0 += 4) {
      float a0 = bb, a1 = bb, a2 = bb, a3 = bb;
#pragma unroll 8
      for (int k = 0; k < 128; ++k) {
        float w = wo3[k * 256 + col];
        a0 = fmaf(x2[(r0 + 0) * 128 + k], w, a0);
        a1 = fmaf(x2[(r0 + 1) * 128 + k], w, a1);
        a2 = fmaf(x2[(r0 + 2) * 128 + k], w, a2);
        a3 = fmaf(x2[(r0 + 3) * 128 + k], w, a3);
      }
      op[(size_t)(r0 + 0) * 256] = a0;
      op[(size_t)(r0 + 1) * 256] = a1;
      op[(size_t)(r0 + 2) * 256] = a2;
      op[(size_t)(r0 + 3) * 256] = a3;
    }
  }
}

extern "C" void kernel_launch(void* const* d_in, const int* in_sizes, int n_in,
                              void* d_out, int out_size, void* d_ws, size_t ws_size,
                              hipStream_t stream) {
  const float* h        = (const float*)d_in[0];
  const float* h_full   = (const float*)d_in[1];
  const int*   z        = (const int*)d_in[2];
  // d_in[3] = mask (unused by reference)
  const float* e_feat   = (const float*)d_in[4];
  const int*   abs_idx  = (const int*)d_in[5];
  const int*   att_dst  = (const int*)d_in[6];
  const float* att_dist = (const float*)d_in[7];
  const float* att_vec  = (const float*)d_in[8];
  const float* w_zemb   = (const float*)d_in[9];
  const float* w1_rad   = (const float*)d_in[10];
  const float* b1_rad   = (const float*)d_in[11];
  const float* w2_rad   = (const float*)d_in[12];
  const float* b2_rad   = (const float*)d_in[13];
  const float* wg1      = (const float*)d_in[14];
  const float* bg1      = (const float*)d_in[15];
  const float* wg2      = (const float*)d_in[16];
  const float* bg2      = (const float*)d_in[17];
  const float* we1      = (const float*)d_in[18];
  const float* be1      = (const float*)d_in[19];
  const float* we2      = (const float*)d_in[20];
  const float* be2      = (const float*)d_in[21];
  const float* wo1      = (const float*)d_in[22];
  const float* bo1      = (const float*)d_in[23];
  const float* wo2      = (const float*)d_in[24];
  const float* bo2      = (const float*)d_in[25];
  const float* wo3      = (const float*)d_in[26];
  const float* bo3      = (const float*)d_in[27];
  float* out = (float*)d_out;

  // workspace layout (~7.2 MB)
  float* a_glob    = (float*)d_ws;                  // MAXACT*128
  float* coef_glob = a_glob + MAXACT * 128;         // MAXACT*192
  float* acc_glob  = coef_glob + MAXACT * 192;      // MAXACT*96
  float* meta_f    = acc_glob + MAXACT * 96;        // MAXACT*4
  float* vabs      = meta_f + MAXACT * 4;           // 64*80
  float* sfull     = vabs + NB * OD_;               // 512*80
  int* widx   = (int*)(sfull + NE_ * OD_);          // 8192
  int* active = widx + FLAT;                        // 4096
  int* meta_b = active + MAXACT;                    // 4096
  int* count  = meta_b + MAXACT;                    // 1

  k_init<<<1536, 256, 0, stream>>>(acc_glob, vabs, widx, count);
  k_scatter<<<16, 256, 0, stream>>>(att_dst, widx);
  k_build<<<32, 256, 0, stream>>>(widx, active, count);
  k_node<<<MAXACT, 128, 0, stream>>>(count, active, widx, att_dist, att_vec, z, w_zemb,
                                     abs_idx, w1_rad, b1_rad, h, wg1, bg1, wg2, bg2,
                                     h_full, a_glob, coef_glob, meta_f, meta_b);
  k_rgemm<<<dim3(18, 64), 256, 0, stream>>>(count, a_glob, coef_glob, w2_rad, b2_rad,
                                            acc_glob);
  k_combine<<<16, 256, 0, stream>>>(count, acc_glob, meta_f, meta_b, vabs);
  k_scales<<<512, 128, 0, stream>>>(e_feat, we1, be1, we2, be2, sfull);
  k_head<<<1024, 256, 0, stream>>>(vabs, sfull, wo1, bo1, wo2, bo2, wo3, bo3, out);
}

// Round 2
// 519.523 us; speedup vs baseline: 1.3761x; 1.3761x over previous
//
#include <hip/hip_runtime.h>
#include <math.h>

#define FLAT   8192
#define NB     64
#define OD_    80
#define NE_    512
#define EATT_  4096
#define MAXACT 4096
// per-node partial slot layout in acc_glob (544 floats/node):
//   chunks 0..11 (A,B): base c*32, 32 slots  -> out_s contributions
//   chunks 12..15 (C) : base 384+(c-12)*16   -> q (scalar coeff for yv)
//   chunks 16..17 (D) : base 448+(c-16)*48   -> out_v direct
#define ACCW 544

__device__ __forceinline__ float silu_f(float x) { return x / (1.f + __expf(-x)); }
__device__ __forceinline__ float sigm_f(float x) { return 1.f / (1.f + __expf(-x)); }

// ---------------- init ----------------
__global__ void k_init(float* vabs, int* widx, int* count) {
  int t = blockIdx.x * 256 + threadIdx.x;
  if (t < FLAT) widx[t] = -1;
  if (t < NB * OD_) vabs[t] = 0.f;
  if (t == 0) *count = 0;
}

// ---------------- scatter: last-write-wins == max edge index ----------------
__global__ void k_scatter(const int* __restrict__ att_dst, int* widx) {
  int i = blockIdx.x * 256 + threadIdx.x;
  if (i < EATT_) atomicMax(&widx[att_dst[i]], i);
}

// ---------------- compact active-node list ----------------
__global__ void k_build(const int* __restrict__ widx, int* active, int* count) {
  int j = blockIdx.x * 256 + threadIdx.x;
  if (j < FLAT && widx[j] >= 0) {
    int p = atomicAdd(count, 1);
    active[p] = j;
  }
}

// ---------------- per active node: rbf, hidden a(128), gate, env, coefs ----------------
__global__ void k_node(const int* __restrict__ count, const int* __restrict__ active,
                       const int* __restrict__ widx,
                       const float* __restrict__ att_dist, const float* __restrict__ att_vec,
                       const int* __restrict__ z, const float* __restrict__ w_zemb,
                       const int* __restrict__ abs_idx,
                       const float* __restrict__ w1_rad, const float* __restrict__ b1_rad,
                       const float* __restrict__ h,
                       const float* __restrict__ wg1, const float* __restrict__ bg1,
                       const float* __restrict__ wg2, const float* __restrict__ bg2,
                       const float* __restrict__ h_full,
                       float* a_glob, float* coef_glob, float* meta_f, int* meta_b) {
  int pos = blockIdx.x;
  if (pos >= *count) return;
  int t = threadIdx.x;  // 128 threads
  __shared__ float win[49];
  __shared__ float yv_s[3];
  __shared__ float red[128];
  __shared__ float sh_d;

  int j = active[pos];
  int b = j >> 7;
  int n = j & 127;
  int e = widx[j];

  if (t == 0) {
    float d = att_dist[e];
    sh_d = d;
    float eps = fmaxf(d, 1e-8f);
    const float s3 = 1.7320508075688772f;
    yv_s[0] = s3 * att_vec[e * 3 + 0] / eps;
    yv_s[1] = s3 * att_vec[e * 3 + 1] / eps;
    yv_s[2] = s3 * att_vec[e * 3 + 2] / eps;
  }
  int nabs = abs_idx[b];
  float isab = (n == nabs) ? 1.f : 0.f;
  if (t < 32) win[t] = w_zemb[z[j] * 32 + t];
  if (t == 32) win[32] = isab;
  if (t >= 33 && t < 49) {
    int k = t - 33;
    float d = att_dist[e];
    float x = (d - (float)k * (1.f / 3.f)) * 3.f;  // width = CUTOFF/(RBF-1) = 1/3
    win[t] = __expf(-0.5f * x * x);
  }
  __syncthreads();

  // hidden a = silu(win @ w1_rad + b1_rad)   (49 -> 128)
  {
    float s = b1_rad[t];
    for (int k = 0; k < 49; ++k) s = fmaf(win[k], w1_rad[k * 128 + t], s);
    a_glob[pos * 128 + t] = silu_f(s);
  }

  // gate MLP hidden (273 -> 128)
  {
    float g = bg1[t];
    const float* habs = h + (size_t)(b * 128 + nabs) * 128;
    const float* hn   = h + (size_t)j * 128;
    for (int c = 0; c < 128; ++c) g = fmaf(habs[c], wg1[c * 128 + t], g);
    for (int c = 0; c < 128; ++c) g = fmaf(hn[c],   wg1[(128 + c) * 128 + t], g);
    for (int k = 0; k < 16; ++k)  g = fmaf(win[33 + k], wg1[(256 + k) * 128 + t], g);
    g = fmaf(isab, wg1[272 * 128 + t], g);
    red[t] = silu_f(g) * wg2[t];
  }
  __syncthreads();

  // per-node contraction coefficients: [s1(64), p*inv_s3(32), v1(96)]
  const float* hf = h_full + (size_t)j * 160;
  if (t < 64) coef_glob[pos * 192 + t] = hf[t];
  if (t >= 64 && t < 96) {
    int i = t - 64;
    float pv = hf[64 + i * 3 + 0] * yv_s[0] + hf[64 + i * 3 + 1] * yv_s[1] +
               hf[64 + i * 3 + 2] * yv_s[2];
    coef_glob[pos * 192 + t] = pv * 0.5773502691896258f;
  }
  if (t < 96) coef_glob[pos * 192 + 96 + t] = hf[64 + t];

  if (t == 0) {
    float tot = 0.f;
    for (int k = 0; k < 128; ++k) tot += red[k];
    tot += bg2[0];
    float gate = sigm_f(tot);
    float d = sh_d;
    float env = (d < 5.f) ? 0.5f * (__cosf(3.14159265358979323846f * d * 0.2f) + 1.f) : 0.f;
    meta_f[pos * 4 + 0] = yv_s[0];
    meta_f[pos * 4 + 1] = yv_s[1];
    meta_f[pos * 4 + 2] = yv_s[2];
    meta_f[pos * 4 + 3] = gate * env;
    meta_b[pos] = b;
  }
}

// ---------------- radial GEMM + fused contraction (register-tiled) ----------------
// grid (18 col-chunks x 64 node-tiles). Block: 64 nodes x 256 cols, K=128.
// Thread: 4 nodes (ty) x 16 cols (tx) in registers. w2 streamed from global
// (read exactly once per block); a staged in LDS. Epilogue contracts tpw with
// per-node coefs via staggered LDS atomics, then plain-stores per-chunk
// partials into acc_glob (no global atomics).
__global__ __launch_bounds__(256, 3) void k_rgemm(const int* __restrict__ count,
                                                  const float* __restrict__ a_glob,
                                                  const float* __restrict__ coef_glob,
                                                  const float* __restrict__ w2,
                                                  const float* __restrict__ b2,
                                                  float* __restrict__ acc_glob) {
  int c = blockIdx.x;          // 0..17
  int nbase = blockIdx.y * 64;
  if (nbase >= *count) return;
  int t = threadIdx.x;
  int tx = t & 15, ty = t >> 4;

  __shared__ float a_s[64 * 132];   // padded: stride 132 (16B-aligned, 2-way max)
  __shared__ float acc_s[64 * 48];

  // stage a (coalesced float4), zero acc_s
  {
    const float4* ag = (const float4*)(a_glob + (size_t)nbase * 128);
#pragma unroll
    for (int it = 0; it < 8; ++it) {
      int f4 = t + it * 256;          // 0..2047
      int r = f4 >> 5, k4 = f4 & 31;
      float4 v = ag[f4];
      *(float4*)&a_s[r * 132 + k4 * 4] = v;
    }
    for (int idx = t; idx < 64 * 48; idx += 256) acc_s[idx] = 0.f;
  }
  __syncthreads();

  int col0 = c * 256 + tx * 16;
  const float* wp = w2 + col0;
  int n0 = ty * 4;
  const float* as0 = a_s + (n0 + 0) * 132;
  const float* as1 = a_s + (n0 + 1) * 132;
  const float* as2 = a_s + (n0 + 2) * 132;
  const float* as3 = a_s + (n0 + 3) * 132;

  float acc[4][16];
#pragma unroll
  for (int i = 0; i < 4; ++i)
#pragma unroll
    for (int j = 0; j < 16; ++j) acc[i][j] = 0.f;

#pragma unroll 4
  for (int k = 0; k < 128; ++k) {
    const float* wrow = wp + k * 4608;
    float4 wv0 = *(const float4*)(wrow + 0);
    float4 wv1 = *(const float4*)(wrow + 4);
    float4 wv2 = *(const float4*)(wrow + 8);
    float4 wv3 = *(const float4*)(wrow + 12);
    float wv[16] = {wv0.x, wv0.y, wv0.z, wv0.w, wv1.x, wv1.y, wv1.z, wv1.w,
                    wv2.x, wv2.y, wv2.z, wv2.w, wv3.x, wv3.y, wv3.z, wv3.w};
    float av[4] = {as0[k], as1[k], as2[k], as3[k]};
#pragma unroll
    for (int i = 0; i < 4; ++i)
#pragma unroll
      for (int j = 0; j < 16; ++j) acc[i][j] = fmaf(av[i], wv[j], acc[i][j]);
  }

  // + bias
  {
    const float* bp = b2 + col0;
    float4 b0 = *(const float4*)(bp + 0);
    float4 b1 = *(const float4*)(bp + 4);
    float4 b2v = *(const float4*)(bp + 8);
    float4 b3 = *(const float4*)(bp + 12);
    float bv[16] = {b0.x, b0.y, b0.z, b0.w, b1.x, b1.y, b1.z, b1.w,
                    b2v.x, b2v.y, b2v.z, b2v.w, b3.x, b3.y, b3.z, b3.w};
#pragma unroll
    for (int i = 0; i < 4; ++i)
#pragma unroll
      for (int j = 0; j < 16; ++j) acc[i][j] += bv[j];
  }

  // contraction into per-block partials (staggered LDS atomics; acc_s zeroed
  // before the first barrier, all writes are atomic -> no barrier needed here)
  if (c < 12) {
    int i_loc = tx >> 1;
    int o0 = (tx & 1) * 16;
    int coff = (c < 8) ? (c * 8 + i_loc) : (64 + (c - 8) * 8 + i_loc);
    int stag = i_loc * 2;
#pragma unroll
    for (int i = 0; i < 4; ++i) {
      float cf = coef_glob[(size_t)(nbase + n0 + i) * 192 + coff];
#pragma unroll
      for (int jj = 0; jj < 16; ++jj) {
        int j = (jj + stag) & 15;
        atomicAdd(&acc_s[(n0 + i) * 32 + o0 + j], acc[i][j] * cf);
      }
    }
  } else if (c < 16) {
    int coff = (c - 12) * 16 + tx;  // s1 coef index
#pragma unroll
    for (int i = 0; i < 4; ++i) {
      float cf = coef_glob[(size_t)(nbase + n0 + i) * 192 + coff];
#pragma unroll
      for (int jj = 0; jj < 16; ++jj) {
        int j = (jj + tx) & 15;
        atomicAdd(&acc_s[(n0 + i) * 16 + j], acc[i][j] * cf);
      }
    }
  } else {
    int ibase = (c - 16) * 16 + tx;
#pragma unroll
    for (int i = 0; i < 4; ++i) {
      size_t cb2 = (size_t)(nbase + n0 + i) * 192 + 96 + (size_t)ibase * 3;
      float c0 = coef_glob[cb2 + 0], c1 = coef_glob[cb2 + 1], c2 = coef_glob[cb2 + 2];
#pragma unroll
      for (int jj = 0; jj < 16; ++jj) {
        int j = (jj + tx) & 15;
        float tpw = acc[i][j];
        atomicAdd(&acc_s[(n0 + i) * 48 + j * 3 + 0], tpw * c0);
        atomicAdd(&acc_s[(n0 + i) * 48 + j * 3 + 1], tpw * c1);
        atomicAdd(&acc_s[(n0 + i) * 48 + j * 3 + 2], tpw * c2);
      }
    }
  }
  __syncthreads();

  int nslot = (c < 12) ? 32 : (c < 16 ? 16 : 48);
  int abase = (c < 12) ? c * 32 : (c < 16 ? 384 + (c - 12) * 16 : 448 + (c - 16) * 48);
  for (int idx = t; idx < 64 * nslot; idx += 256) {
    int r = idx / nslot, s = idx - r * nslot;
    acc_glob[(size_t)(nbase + r) * ACCW + abase + s] = acc_s[idx];
  }
}

// ---------------- reduce 544 partials/node -> v_abs[b][80] ----------------
__global__ void k_combine(const int* __restrict__ count, const float* __restrict__ acc_glob,
                          const float* __restrict__ meta_f, const int* __restrict__ meta_b,
                          float* vabs) {
  int g = blockIdx.x * 256 + threadIdx.x;
  int pos = g / 96, slot = g - pos * 96;
  if (pos >= *count) return;
  const float* acc = acc_glob + (size_t)pos * ACCW;
  float sc = meta_f[pos * 4 + 3] * 0.10206207261596577f;  // gate*env / sqrt(96)
  float* vb = vabs + meta_b[pos] * 80;
  if (slot < 32) {
    float s = 0.f;
#pragma unroll
    for (int cc = 0; cc < 12; ++cc) s += acc[cc * 32 + slot];
    atomicAdd(&vb[slot], s * sc);
  } else if (slot < 48) {
    int o = slot - 32;
    float q = acc[384 + o] + acc[384 + 16 + o] + acc[384 + 32 + o] + acc[384 + 48 + o];
    q *= sc;
    atomicAdd(&vb[32 + o * 3 + 0], q * meta_f[pos * 4 + 0]);
    atomicAdd(&vb[32 + o * 3 + 1], q * meta_f[pos * 4 + 1]);
    atomicAdd(&vb[32 + o * 3 + 2], q * meta_f[pos * 4 + 2]);
  } else {
    int s2 = slot - 48;
    float dsum = acc[448 + s2] + acc[448 + 48 + s2];
    atomicAdd(&vb[32 + s2], dsum * sc);
  }
}

// ---------------- edge-feature scales -> scale_full[512][80] ----------------
__global__ void k_scales(const float* __restrict__ e_feat,
                         const float* __restrict__ we1, const float* __restrict__ be1,
                         const float* __restrict__ we2, const float* __restrict__ be2,
                         float* sfull) {
  int row = blockIdx.x;  // 512
  int t = threadIdx.x;   // 128
  __shared__ float hid[128];
  const float* ef = e_feat + row * 16;
  float s = be1[t];
  for (int k = 0; k < 16; ++k) s = fmaf(ef[k], we1[k * 128 + t], s);
  hid[t] = silu_f(s);
  __syncthreads();
  if (t < 48) {
    float o = be2[t];
    for (int k = 0; k < 128; ++k) o = fmaf(hid[k], we2[k * 48 + t], o);
    if (t < 32) sfull[row * 80 + t] = o;
    else {
      int oo = t - 32;
      sfull[row * 80 + 32 + oo * 3 + 0] = o;
      sfull[row * 80 + 32 + oo * 3 + 1] = o;
      sfull[row * 80 + 32 + oo * 3 + 2] = o;
    }
  }
}

// ---------------- head MLP: 32 rows/block, transposed LDS activations ----------------
__global__ __launch_bounds__(256) void k_head(const float* __restrict__ vabs,
                                              const float* __restrict__ sfull,
                                              const float* __restrict__ wo1, const float* __restrict__ bo1,
                                              const float* __restrict__ wo2, const float* __restrict__ bo2,
                                              const float* __restrict__ wo3, const float* __restrict__ bo3,
                                              float* __restrict__ out) {
  int blk = blockIdx.x;  // 1024 = 64 b x 16 e-tiles
  int b = blk >> 4;
  int e0 = (blk & 15) * 32;
  int t = threadIdx.x;

  __shared__ float va[80];
  __shared__ float smem[2592 + 4608 + 4608];  // sfl | x1_t | x2_t(alias inv_t)
  float* sfl  = smem;            // [32][81]
  float* x1t  = smem + 2592;     // [128][36]
  float* x2t  = smem + 7200;     // [128][36]
  float* invt = x2t;             // [48][36], dead before x2t written

  if (t < 80) va[t] = vabs[b * 80 + t];
  for (int idx = t; idx < 32 * 80; idx += 256) {
    int r = idx / 80, cc = idx - r * 80;
    sfl[r * 81 + cc] = sfull[e0 * 80 + idx];
  }
  __syncthreads();

  // inv (transposed [c][r], stride 36)
  for (int idx = t; idx < 48 * 32; idx += 256) {
    int cd = idx >> 5, r = idx & 31;
    float v;
    if (cd < 32) v = va[cd] * sfl[r * 81 + cd];
    else {
      int base = 32 + (cd - 32) * 3;
      float m0 = va[base + 0] * sfl[r * 81 + base + 0];
      float m1 = va[base + 1] * sfl[r * 81 + base + 1];
      float m2 = va[base + 2] * sfl[r * 81 + base + 2];
      v = sqrtf(m0 * m0 + m1 * m1 + m2 * m2 + 1e-12f);
    }
    invt[cd * 36 + r] = v;
  }
  __syncthreads();

  // L1: 48 -> 128, thread = (col, half-rows), 16 rows in registers
  {
    int col = t & 127, r0 = (t >> 7) * 16;
    float a[16];
    float bb = bo1[col];
#pragma unroll
    for (int r = 0; r < 16; ++r) a[r] = bb;
    for (int k = 0; k < 48; ++k) {
      float w = wo1[k * 128 + col];
      const float* xp = &invt[k * 36 + r0];
      float4 x0 = *(const float4*)(xp + 0);
      float4 x1 = *(const float4*)(xp + 4);
      float4 x2 = *(const float4*)(xp + 8);
      float4 x3 = *(const float4*)(xp + 12);
      float xs[16] = {x0.x, x0.y, x0.z, x0.w, x1.x, x1.y, x1.z, x1.w,
                      x2.x, x2.y, x2.z, x2.w, x3.x, x3.y, x3.z, x3.w};
#pragma unroll
      for (int r = 0; r < 16; ++r) a[r] = fmaf(xs[r], w, a[r]);
    }
#pragma unroll
    for (int r = 0; r < 16; ++r) x1t[col * 36 + r0 + r] = silu_f(a[r]);
  }
  __syncthreads();

  // L2: 128 -> 128
  {
    int col = t & 127, r0 = (t >> 7) * 16;
    float a[16];
    float bb = bo2[col];
#pragma unroll
    for (int r = 0; r < 16; ++r) a[r] = bb;
    for (int k = 0; k < 128; ++k) {
      float w = wo2[k * 128 + col];
      const float* xp = &x1t[k * 36 + r0];
      float4 x0 = *(const float4*)(xp + 0);
      float4 x1 = *(const float4*)(xp + 4);
      float4 x2 = *(const float4*)(xp + 8);
      float4 x3 = *(const float4*)(xp + 12);
      float xs[16] = {x0.x, x0.y, x0.z, x0.w, x1.x, x1.y, x1.z, x1.w,
                      x2.x, x2.y, x2.z, x2.w, x3.x, x3.y, x3.z, x3.w};
#pragma unroll
      for (int r = 0; r < 16; ++r) a[r] = fmaf(xs[r], w, a[r]);
    }
#pragma unroll
    for (int r = 0; r < 16; ++r) x2t[col * 36 + r0 + r] = silu_f(a[r]);
  }
  __syncthreads();

  // L3: 128 -> 256, thread = col, all 32 rows in registers
  {
    int col = t;
    float a[32];
    float bb = bo3[col];
#pragma unroll
    for (int r = 0; r < 32; ++r) a[r] = bb;
    for (int k = 0; k < 128; ++k) {
      float w = wo3[k * 256 + col];
      const float* xp = &x2t[k * 36];
#pragma unroll
      for (int q = 0; q < 8; ++q) {
        float4 xv = *(const float4*)(xp + q * 4);
        a[q * 4 + 0] = fmaf(xv.x, w, a[q * 4 + 0]);
        a[q * 4 + 1] = fmaf(xv.y, w, a[q * 4 + 1]);
        a[q * 4 + 2] = fmaf(xv.z, w, a[q * 4 + 2]);
        a[q * 4 + 3] = fmaf(xv.w, w, a[q * 4 + 3]);
      }
    }
    float* op = out + ((size_t)(b * 512 + e0)) * 256 + col;
#pragma unroll
    for (int r = 0; r < 32; ++r) op[(size_t)r * 256] = a[r];
  }
}

extern "C" void kernel_launch(void* const* d_in, const int* in_sizes, int n_in,
                              void* d_out, int out_size, void* d_ws, size_t ws_size,
                              hipStream_t stream) {
  const float* h        = (const float*)d_in[0];
  const float* h_full   = (const float*)d_in[1];
  const int*   z        = (const int*)d_in[2];
  const float* e_feat   = (const float*)d_in[4];
  const int*   abs_idx  = (const int*)d_in[5];
  const int*   att_dst  = (const int*)d_in[6];
  const float* att_dist = (const float*)d_in[7];
  const float* att_vec  = (const float*)d_in[8];
  const float* w_zemb   = (const float*)d_in[9];
  const float* w1_rad   = (const float*)d_in[10];
  const float* b1_rad   = (const float*)d_in[11];
  const float* w2_rad   = (const float*)d_in[12];
  const float* b2_rad   = (const float*)d_in[13];
  const float* wg1      = (const float*)d_in[14];
  const float* bg1      = (const float*)d_in[15];
  const float* wg2      = (const float*)d_in[16];
  const float* bg2      = (const float*)d_in[17];
  const float* we1      = (const float*)d_in[18];
  const float* be1      = (const float*)d_in[19];
  const float* we2      = (const float*)d_in[20];
  const float* be2      = (const float*)d_in[21];
  const float* wo1      = (const float*)d_in[22];
  const float* bo1      = (const float*)d_in[23];
  const float* wo2      = (const float*)d_in[24];
  const float* bo2      = (const float*)d_in[25];
  const float* wo3      = (const float*)d_in[26];
  const float* bo3      = (const float*)d_in[27];
  float* out = (float*)d_out;

  // workspace layout (~14.3 MB)
  float* a_glob    = (float*)d_ws;                   // MAXACT*128
  float* coef_glob = a_glob + MAXACT * 128;          // MAXACT*192
  float* acc_glob  = coef_glob + MAXACT * 192;       // MAXACT*544
  float* meta_f    = acc_glob + (size_t)MAXACT * ACCW;  // MAXACT*4
  float* vabs      = meta_f + MAXACT * 4;            // 64*80
  float* sfull     = vabs + NB * OD_;                // 512*80
  int* widx   = (int*)(sfull + NE_ * OD_);           // 8192
  int* active = widx + FLAT;                         // 4096
  int* meta_b = active + MAXACT;                     // 4096
  int* count  = meta_b + MAXACT;                     // 1

  k_init<<<32, 256, 0, stream>>>(vabs, widx, count);
  k_scatter<<<16, 256, 0, stream>>>(att_dst, widx);
  k_build<<<32, 256, 0, stream>>>(widx, active, count);
  k_node<<<MAXACT, 128, 0, stream>>>(count, active, widx, att_dist, att_vec, z, w_zemb,
                                     abs_idx, w1_rad, b1_rad, h, wg1, bg1, wg2, bg2,
                                     h_full, a_glob, coef_glob, meta_f, meta_b);
  k_rgemm<<<dim3(18, 64), 256, 0, stream>>>(count, a_glob, coef_glob, w2_rad, b2_rad,
                                            acc_glob);
  k_combine<<<1536, 256, 0, stream>>>(count, acc_glob, meta_f, meta_b, vabs);
  k_scales<<<512, 128, 0, stream>>>(e_feat, we1, be1, we2, be2, sfull);
  k_head<<<1024, 256, 0, stream>>>(vabs, sfull, wo1, bo1, wo2, bo2, wo3, bo3, out);
}

// Round 3
// 376.593 us; speedup vs baseline: 1.8984x; 1.3795x over previous
//
#include <hip/hip_runtime.h>
#include <math.h>

#define FLAT   8192
#define NB     64
#define OD_    80
#define NE_    512
#define EATT_  4096
#define MAXACT 4096
// per-node partial slot layout in acc_glob (544 floats/node):
//   chunks 0..11 (A,B): base c*32, 32 slots  -> out_s contributions
//   chunks 12..15 (C) : base 384+(c-12)*16   -> q (scalar coeff for yv)
//   chunks 16..17 (D) : base 448+(c-16)*48, layout comp*16+o -> out_v direct
#define ACCW 544

__device__ __forceinline__ float silu_f(float x) { return x / (1.f + __expf(-x)); }
__device__ __forceinline__ float sigm_f(float x) { return 1.f / (1.f + __expf(-x)); }

// ---------------- init ----------------
__global__ void k_init(float* vabs, int* widx, int* count) {
  int t = blockIdx.x * 256 + threadIdx.x;
  if (t < FLAT) widx[t] = -1;
  if (t < NB * OD_) vabs[t] = 0.f;
  if (t == 0) *count = 0;
}

// ---------------- scatter: last-write-wins == max edge index ----------------
__global__ void k_scatter(const int* __restrict__ att_dst, int* widx) {
  int i = blockIdx.x * 256 + threadIdx.x;
  if (i < EATT_) atomicMax(&widx[att_dst[i]], i);
}

// ---------------- compact active-node list ----------------
__global__ void k_build(const int* __restrict__ widx, int* active, int* count) {
  int j = blockIdx.x * 256 + threadIdx.x;
  if (j < FLAT && widx[j] >= 0) {
    int p = atomicAdd(count, 1);
    active[p] = j;
  }
}

// ---------------- per active node: rbf, hidden a(128), gate, env, coefs ----------------
__global__ void k_node(const int* __restrict__ count, const int* __restrict__ active,
                       const int* __restrict__ widx,
                       const float* __restrict__ att_dist, const float* __restrict__ att_vec,
                       const int* __restrict__ z, const float* __restrict__ w_zemb,
                       const int* __restrict__ abs_idx,
                       const float* __restrict__ w1_rad, const float* __restrict__ b1_rad,
                       const float* __restrict__ h,
                       const float* __restrict__ wg1, const float* __restrict__ bg1,
                       const float* __restrict__ wg2, const float* __restrict__ bg2,
                       const float* __restrict__ h_full,
                       float* a_glob, float* coef_glob, float* meta_f, int* meta_b) {
  int pos = blockIdx.x;
  if (pos >= *count) return;
  int t = threadIdx.x;  // 128 threads
  __shared__ float win[49];
  __shared__ float yv_s[3];
  __shared__ float red[128];
  __shared__ float sh_d;

  int j = active[pos];
  int b = j >> 7;
  int n = j & 127;
  int e = widx[j];

  if (t == 0) {
    float d = att_dist[e];
    sh_d = d;
    float eps = fmaxf(d, 1e-8f);
    const float s3 = 1.7320508075688772f;
    yv_s[0] = s3 * att_vec[e * 3 + 0] / eps;
    yv_s[1] = s3 * att_vec[e * 3 + 1] / eps;
    yv_s[2] = s3 * att_vec[e * 3 + 2] / eps;
  }
  int nabs = abs_idx[b];
  float isab = (n == nabs) ? 1.f : 0.f;
  if (t < 32) win[t] = w_zemb[z[j] * 32 + t];
  if (t == 32) win[32] = isab;
  if (t >= 33 && t < 49) {
    int k = t - 33;
    float d = att_dist[e];
    float x = (d - (float)k * (1.f / 3.f)) * 3.f;  // width = CUTOFF/(RBF-1) = 1/3
    win[t] = __expf(-0.5f * x * x);
  }
  __syncthreads();

  // hidden a = silu(win @ w1_rad + b1_rad)   (49 -> 128)
  {
    float s = b1_rad[t];
    for (int k = 0; k < 49; ++k) s = fmaf(win[k], w1_rad[k * 128 + t], s);
    a_glob[pos * 128 + t] = silu_f(s);
  }

  // gate MLP hidden (273 -> 128)
  {
    float g = bg1[t];
    const float* habs = h + (size_t)(b * 128 + nabs) * 128;
    const float* hn   = h + (size_t)j * 128;
    for (int c = 0; c < 128; ++c) g = fmaf(habs[c], wg1[c * 128 + t], g);
    for (int c = 0; c < 128; ++c) g = fmaf(hn[c],   wg1[(128 + c) * 128 + t], g);
    for (int k = 0; k < 16; ++k)  g = fmaf(win[33 + k], wg1[(256 + k) * 128 + t], g);
    g = fmaf(isab, wg1[272 * 128 + t], g);
    red[t] = silu_f(g) * wg2[t];
  }
  __syncthreads();

  // per-node contraction coefficients: [s1(64), p*inv_s3(32), v1(96)]
  const float* hf = h_full + (size_t)j * 160;
  if (t < 64) coef_glob[pos * 192 + t] = hf[t];
  if (t >= 64 && t < 96) {
    int i = t - 64;
    float pv = hf[64 + i * 3 + 0] * yv_s[0] + hf[64 + i * 3 + 1] * yv_s[1] +
               hf[64 + i * 3 + 2] * yv_s[2];
    coef_glob[pos * 192 + t] = pv * 0.5773502691896258f;
  }
  if (t < 96) coef_glob[pos * 192 + 96 + t] = hf[64 + t];

  if (t == 0) {
    float tot = 0.f;
    for (int k = 0; k < 128; ++k) tot += red[k];
    tot += bg2[0];
    float gate = sigm_f(tot);
    float d = sh_d;
    float env = (d < 5.f) ? 0.5f * (__cosf(3.14159265358979323846f * d * 0.2f) + 1.f) : 0.f;
    meta_f[pos * 4 + 0] = yv_s[0];
    meta_f[pos * 4 + 1] = yv_s[1];
    meta_f[pos * 4 + 2] = yv_s[2];
    meta_f[pos * 4 + 3] = gate * env;
    meta_b[pos] = b;
  }
}

// ---------------- radial GEMM + fused contraction (register-tiled) ----------------
// grid (18 col-chunks x 64 node-tiles). Block: 64 nodes x 256 cols, K=128.
// Thread: 4 nodes (ty) x 16 cols (tx) in registers, ALL indices compile-time
// (round-2 lesson: runtime indexing of acc[][] demoted it to scratch -> 118 MB
// HBM writes). Contraction over the i-dimension done with __shfl_xor lane
// reductions (i lives across tx lanes), then plain coalesced float4 stores.
__global__ __launch_bounds__(256, 3) void k_rgemm(const int* __restrict__ count,
                                                  const float* __restrict__ a_glob,
                                                  const float* __restrict__ coef_glob,
                                                  const float* __restrict__ w2,
                                                  const float* __restrict__ b2,
                                                  float* __restrict__ acc_glob) {
  int c = blockIdx.x;          // 0..17
  int nbase = blockIdx.y * 64;
  if (nbase >= *count) return;
  int t = threadIdx.x;
  int tx = t & 15, ty = t >> 4;

  __shared__ float a_s[64 * 132];   // stride 132: 16B-aligned, at most 2-way bank alias

  // stage a (coalesced float4)
  {
    const float4* ag = (const float4*)(a_glob + (size_t)nbase * 128);
#pragma unroll
    for (int it = 0; it < 8; ++it) {
      int f4 = t + it * 256;          // 0..2047
      int r = f4 >> 5, k4 = f4 & 31;
      *(float4*)&a_s[r * 132 + k4 * 4] = ag[f4];
    }
  }
  __syncthreads();

  int col0 = c * 256 + tx * 16;
  const float* wp = w2 + col0;
  int n0 = ty * 4;

  float acc[4][16];
#pragma unroll
  for (int i = 0; i < 4; ++i)
#pragma unroll
    for (int j = 0; j < 16; ++j) acc[i][j] = 0.f;

  for (int k4 = 0; k4 < 32; ++k4) {
    float4 av[4];
#pragma unroll
    for (int i = 0; i < 4; ++i)
      av[i] = *(const float4*)&a_s[(n0 + i) * 132 + k4 * 4];
#pragma unroll
    for (int kk = 0; kk < 4; ++kk) {
      const float* wrow = wp + (size_t)(k4 * 4 + kk) * 4608;
      float4 w0 = *(const float4*)(wrow + 0);
      float4 w1 = *(const float4*)(wrow + 4);
      float4 w2v = *(const float4*)(wrow + 8);
      float4 w3 = *(const float4*)(wrow + 12);
#pragma unroll
      for (int i = 0; i < 4; ++i) {
        float a = (kk == 0) ? av[i].x : (kk == 1) ? av[i].y : (kk == 2) ? av[i].z : av[i].w;
        acc[i][0]  = fmaf(a, w0.x,  acc[i][0]);
        acc[i][1]  = fmaf(a, w0.y,  acc[i][1]);
        acc[i][2]  = fmaf(a, w0.z,  acc[i][2]);
        acc[i][3]  = fmaf(a, w0.w,  acc[i][3]);
        acc[i][4]  = fmaf(a, w1.x,  acc[i][4]);
        acc[i][5]  = fmaf(a, w1.y,  acc[i][5]);
        acc[i][6]  = fmaf(a, w1.z,  acc[i][6]);
        acc[i][7]  = fmaf(a, w1.w,  acc[i][7]);
        acc[i][8]  = fmaf(a, w2v.x, acc[i][8]);
        acc[i][9]  = fmaf(a, w2v.y, acc[i][9]);
        acc[i][10] = fmaf(a, w2v.z, acc[i][10]);
        acc[i][11] = fmaf(a, w2v.w, acc[i][11]);
        acc[i][12] = fmaf(a, w3.x,  acc[i][12]);
        acc[i][13] = fmaf(a, w3.y,  acc[i][13]);
        acc[i][14] = fmaf(a, w3.z,  acc[i][14]);
        acc[i][15] = fmaf(a, w3.w,  acc[i][15]);
      }
    }
  }

  // + bias (tpw = a@w2 + b2)
  {
    const float* bp = b2 + col0;
    float4 b0 = *(const float4*)(bp + 0);
    float4 b1 = *(const float4*)(bp + 4);
    float4 b2v = *(const float4*)(bp + 8);
    float4 b3 = *(const float4*)(bp + 12);
#pragma unroll
    for (int i = 0; i < 4; ++i) {
      acc[i][0] += b0.x;  acc[i][1] += b0.y;  acc[i][2] += b0.z;  acc[i][3] += b0.w;
      acc[i][4] += b1.x;  acc[i][5] += b1.y;  acc[i][6] += b1.z;  acc[i][7] += b1.w;
      acc[i][8] += b2v.x; acc[i][9] += b2v.y; acc[i][10] += b2v.z; acc[i][11] += b2v.w;
      acc[i][12] += b3.x; acc[i][13] += b3.y; acc[i][14] += b3.z; acc[i][15] += b3.w;
    }
  }

  if (c < 12) {
    // A/B chunks: col = i*32 + o; i_loc = tx>>1, o0 = (tx&1)*16.
    // coef index = c*8 + i_loc (A: s1 at 0..63; B: 64+(c-8)*8+i_loc == c*8+i_loc).
    int i_loc = tx >> 1;
    int coff = c * 8 + i_loc;
    float cf[4];
#pragma unroll
    for (int i = 0; i < 4; ++i)
      cf[i] = coef_glob[(size_t)(nbase + n0 + i) * 192 + coff];
    float vred[4][16];
#pragma unroll
    for (int j = 0; j < 16; ++j) {
#pragma unroll
      for (int i = 0; i < 4; ++i) {
        float v = acc[i][j] * cf[i];
        v += __shfl_xor(v, 2);
        v += __shfl_xor(v, 4);
        v += __shfl_xor(v, 8);
        vred[i][j] = v;
      }
    }
    if (tx < 2) {
      int o0 = tx * 16;
#pragma unroll
      for (int i = 0; i < 4; ++i) {
        float* dst = &acc_glob[(size_t)(nbase + n0 + i) * ACCW + c * 32 + o0];
        *(float4*)(dst + 0)  = make_float4(vred[i][0], vred[i][1], vred[i][2], vred[i][3]);
        *(float4*)(dst + 4)  = make_float4(vred[i][4], vred[i][5], vred[i][6], vred[i][7]);
        *(float4*)(dst + 8)  = make_float4(vred[i][8], vred[i][9], vred[i][10], vred[i][11]);
        *(float4*)(dst + 12) = make_float4(vred[i][12], vred[i][13], vred[i][14], vred[i][15]);
      }
    }
  } else if (c < 16) {
    // C chunks: col = i*16 + o; i = (c-12)*16 + tx; uses s1 coefs (0..63)
    int coff = (c - 12) * 16 + tx;
    float cf[4];
#pragma unroll
    for (int i = 0; i < 4; ++i)
      cf[i] = coef_glob[(size_t)(nbase + n0 + i) * 192 + coff];
    float vred[4][16];
#pragma unroll
    for (int j = 0; j < 16; ++j) {
#pragma unroll
      for (int i = 0; i < 4; ++i) {
        float v = acc[i][j] * cf[i];
        v += __shfl_xor(v, 1);
        v += __shfl_xor(v, 2);
        v += __shfl_xor(v, 4);
        v += __shfl_xor(v, 8);
        vred[i][j] = v;
      }
    }
    if (tx == 0) {
#pragma unroll
      for (int i = 0; i < 4; ++i) {
        float* dst = &acc_glob[(size_t)(nbase + n0 + i) * ACCW + 384 + (c - 12) * 16];
        *(float4*)(dst + 0)  = make_float4(vred[i][0], vred[i][1], vred[i][2], vred[i][3]);
        *(float4*)(dst + 4)  = make_float4(vred[i][4], vred[i][5], vred[i][6], vred[i][7]);
        *(float4*)(dst + 8)  = make_float4(vred[i][8], vred[i][9], vred[i][10], vred[i][11]);
        *(float4*)(dst + 12) = make_float4(vred[i][12], vred[i][13], vred[i][14], vred[i][15]);
      }
    }
  } else {
    // D chunks: col = i*16 + o; i = (c-16)*16 + tx; v1 3-vector coefs.
    // Partial layout per chunk: comp*16 + o (keeps stores float4).
    int ibase = (c - 16) * 16 + tx;
    float c0[4], c1[4], c2[4];
#pragma unroll
    for (int i = 0; i < 4; ++i) {
      size_t cb = (size_t)(nbase + n0 + i) * 192 + 96 + (size_t)ibase * 3;
      c0[i] = coef_glob[cb + 0];
      c1[i] = coef_glob[cb + 1];
      c2[i] = coef_glob[cb + 2];
    }
#pragma unroll
    for (int comp = 0; comp < 3; ++comp) {
      float vred[4][16];
#pragma unroll
      for (int j = 0; j < 16; ++j) {
#pragma unroll
        for (int i = 0; i < 4; ++i) {
          float cc = (comp == 0) ? c0[i] : (comp == 1) ? c1[i] : c2[i];
          float v = acc[i][j] * cc;
          v += __shfl_xor(v, 1);
          v += __shfl_xor(v, 2);
          v += __shfl_xor(v, 4);
          v += __shfl_xor(v, 8);
          vred[i][j] = v;
        }
      }
      if (tx == 0) {
#pragma unroll
        for (int i = 0; i < 4; ++i) {
          float* dst = &acc_glob[(size_t)(nbase + n0 + i) * ACCW + 448 + (c - 16) * 48 + comp * 16];
          *(float4*)(dst + 0)  = make_float4(vred[i][0], vred[i][1], vred[i][2], vred[i][3]);
          *(float4*)(dst + 4)  = make_float4(vred[i][4], vred[i][5], vred[i][6], vred[i][7]);
          *(float4*)(dst + 8)  = make_float4(vred[i][8], vred[i][9], vred[i][10], vred[i][11]);
          *(float4*)(dst + 12) = make_float4(vred[i][12], vred[i][13], vred[i][14], vred[i][15]);
        }
      }
    }
  }
}

// ---------------- reduce 544 partials/node -> v_abs[b][80] ----------------
__global__ void k_combine(const int* __restrict__ count, const float* __restrict__ acc_glob,
                          const float* __restrict__ meta_f, const int* __restrict__ meta_b,
                          float* vabs) {
  int g = blockIdx.x * 256 + threadIdx.x;
  int pos = g / 96, slot = g - pos * 96;
  if (pos >= *count) return;
  const float* acc = acc_glob + (size_t)pos * ACCW;
  float sc = meta_f[pos * 4 + 3] * 0.10206207261596577f;  // gate*env / sqrt(96)
  float* vb = vabs + meta_b[pos] * 80;
  if (slot < 32) {
    float s = 0.f;
#pragma unroll
    for (int cc = 0; cc < 12; ++cc) s += acc[cc * 32 + slot];
    atomicAdd(&vb[slot], s * sc);
  } else if (slot < 48) {
    int o = slot - 32;
    float q = acc[384 + o] + acc[384 + 16 + o] + acc[384 + 32 + o] + acc[384 + 48 + o];
    q *= sc;
    atomicAdd(&vb[32 + o * 3 + 0], q * meta_f[pos * 4 + 0]);
    atomicAdd(&vb[32 + o * 3 + 1], q * meta_f[pos * 4 + 1]);
    atomicAdd(&vb[32 + o * 3 + 2], q * meta_f[pos * 4 + 2]);
  } else {
    int s2 = slot - 48;         // s2 = o*3 + comp in output layout
    int o = s2 / 3, comp = s2 - o * 3;
    float dsum = acc[448 + comp * 16 + o] + acc[496 + comp * 16 + o];
    atomicAdd(&vb[32 + s2], dsum * sc);
  }
}

// ---------------- edge-feature scales -> scale_full[512][80] ----------------
__global__ void k_scales(const float* __restrict__ e_feat,
                         const float* __restrict__ we1, const float* __restrict__ be1,
                         const float* __restrict__ we2, const float* __restrict__ be2,
                         float* sfull) {
  int row = blockIdx.x;  // 512
  int t = threadIdx.x;   // 128
  __shared__ float hid[128];
  const float* ef = e_feat + row * 16;
  float s = be1[t];
  for (int k = 0; k < 16; ++k) s = fmaf(ef[k], we1[k * 128 + t], s);
  hid[t] = silu_f(s);
  __syncthreads();
  if (t < 48) {
    float o = be2[t];
    for (int k = 0; k < 128; ++k) o = fmaf(hid[k], we2[k * 48 + t], o);
    if (t < 32) sfull[row * 80 + t] = o;
    else {
      int oo = t - 32;
      sfull[row * 80 + 32 + oo * 3 + 0] = o;
      sfull[row * 80 + 32 + oo * 3 + 1] = o;
      sfull[row * 80 + 32 + oo * 3 + 2] = o;
    }
  }
}

// ---------------- head MLP: 32 rows/block, transposed LDS activations ----------------
__global__ __launch_bounds__(256) void k_head(const float* __restrict__ vabs,
                                              const float* __restrict__ sfull,
                                              const float* __restrict__ wo1, const float* __restrict__ bo1,
                                              const float* __restrict__ wo2, const float* __restrict__ bo2,
                                              const float* __restrict__ wo3, const float* __restrict__ bo3,
                                              float* __restrict__ out) {
  int blk = blockIdx.x;  // 1024 = 64 b x 16 e-tiles
  int b = blk >> 4;
  int e0 = (blk & 15) * 32;
  int t = threadIdx.x;

  __shared__ float va[80];
  __shared__ float smem[2592 + 4608 + 4608];  // sfl | x1_t | x2_t(alias inv_t)
  float* sfl  = smem;            // [32][81]
  float* x1t  = smem + 2592;     // [128][36]
  float* x2t  = smem + 7200;     // [128][36]
  float* invt = x2t;             // [48][36], dead before x2t written

  if (t < 80) va[t] = vabs[b * 80 + t];
  for (int idx = t; idx < 32 * 80; idx += 256) {
    int r = idx / 80, cc = idx - r * 80;
    sfl[r * 81 + cc] = sfull[e0 * 80 + idx];
  }
  __syncthreads();

  // inv (transposed [c][r], stride 36)
  for (int idx = t; idx < 48 * 32; idx += 256) {
    int cd = idx >> 5, r = idx & 31;
    float v;
    if (cd < 32) v = va[cd] * sfl[r * 81 + cd];
    else {
      int base = 32 + (cd - 32) * 3;
      float m0 = va[base + 0] * sfl[r * 81 + base + 0];
      float m1 = va[base + 1] * sfl[r * 81 + base + 1];
      float m2 = va[base + 2] * sfl[r * 81 + base + 2];
      v = sqrtf(m0 * m0 + m1 * m1 + m2 * m2 + 1e-12f);
    }
    invt[cd * 36 + r] = v;
  }
  __syncthreads();

  // L1: 48 -> 128, thread = (col, half-rows), 16 rows in registers
  {
    int col = t & 127, r0 = (t >> 7) * 16;
    float a[16];
    float bb = bo1[col];
#pragma unroll
    for (int r = 0; r < 16; ++r) a[r] = bb;
    for (int k = 0; k < 48; ++k) {
      float w = wo1[k * 128 + col];
      const float* xp = &invt[k * 36 + r0];
      float4 x0 = *(const float4*)(xp + 0);
      float4 x1 = *(const float4*)(xp + 4);
      float4 x2 = *(const float4*)(xp + 8);
      float4 x3 = *(const float4*)(xp + 12);
      float xs[16] = {x0.x, x0.y, x0.z, x0.w, x1.x, x1.y, x1.z, x1.w,
                      x2.x, x2.y, x2.z, x2.w, x3.x, x3.y, x3.z, x3.w};
#pragma unroll
      for (int r = 0; r < 16; ++r) a[r] = fmaf(xs[r], w, a[r]);
    }
#pragma unroll
    for (int r = 0; r < 16; ++r) x1t[col * 36 + r0 + r] = silu_f(a[r]);
  }
  __syncthreads();

  // L2: 128 -> 128
  {
    int col = t & 127, r0 = (t >> 7) * 16;
    float a[16];
    float bb = bo2[col];
#pragma unroll
    for (int r = 0; r < 16; ++r) a[r] = bb;
    for (int k = 0; k < 128; ++k) {
      float w = wo2[k * 128 + col];
      const float* xp = &x1t[k * 36 + r0];
      float4 x0 = *(const float4*)(xp + 0);
      float4 x1 = *(const float4*)(xp + 4);
      float4 x2 = *(const float4*)(xp + 8);
      float4 x3 = *(const float4*)(xp + 12);
      float xs[16] = {x0.x, x0.y, x0.z, x0.w, x1.x, x1.y, x1.z, x1.w,
                      x2.x, x2.y, x2.z, x2.w, x3.x, x3.y, x3.z, x3.w};
#pragma unroll
      for (int r = 0; r < 16; ++r) a[r] = fmaf(xs[r], w, a[r]);
    }
#pragma unroll
    for (int r = 0; r < 16; ++r) x2t[col * 36 + r0 + r] = silu_f(a[r]);
  }
  __syncthreads();

  // L3: 128 -> 256, thread = col, all 32 rows in registers
  {
    int col = t;
    float a[32];
    float bb = bo3[col];
#pragma unroll
    for (int r = 0; r < 32; ++r) a[r] = bb;
    for (int k = 0; k < 128; ++k) {
      float w = wo3[k * 256 + col];
      const float* xp = &x2t[k * 36];
#pragma unroll
      for (int q = 0; q < 8; ++q) {
        float4 xv = *(const float4*)(xp + q * 4);
        a[q * 4 + 0] = fmaf(xv.x, w, a[q * 4 + 0]);
        a[q * 4 + 1] = fmaf(xv.y, w, a[q * 4 + 1]);
        a[q * 4 + 2] = fmaf(xv.z, w, a[q * 4 + 2]);
        a[q * 4 + 3] = fmaf(xv.w, w, a[q * 4 + 3]);
      }
    }
    float* op = out + ((size_t)(b * 512 + e0)) * 256 + col;
#pragma unroll
    for (int r = 0; r < 32; ++r) op[(size_t)r * 256] = a[r];
  }
}

extern "C" void kernel_launch(void* const* d_in, const int* in_sizes, int n_in,
                              void* d_out, int out_size, void* d_ws, size_t ws_size,
                              hipStream_t stream) {
  const float* h        = (const float*)d_in[0];
  const float* h_full   = (const float*)d_in[1];
  const int*   z        = (const int*)d_in[2];
  const float* e_feat   = (const float*)d_in[4];
  const int*   abs_idx  = (const int*)d_in[5];
  const int*   att_dst  = (const int*)d_in[6];
  const float* att_dist = (const float*)d_in[7];
  const float* att_vec  = (const float*)d_in[8];
  const float* w_zemb   = (const float*)d_in[9];
  const float* w1_rad   = (const float*)d_in[10];
  const float* b1_rad   = (const float*)d_in[11];
  const float* w2_rad   = (const float*)d_in[12];
  const float* b2_rad   = (const float*)d_in[13];
  const float* wg1      = (const float*)d_in[14];
  const float* bg1      = (const float*)d_in[15];
  const float* wg2      = (const float*)d_in[16];
  const float* bg2      = (const float*)d_in[17];
  const float* we1      = (const float*)d_in[18];
  const float* be1      = (const float*)d_in[19];
  const float* we2      = (const float*)d_in[20];
  const float* be2      = (const float*)d_in[21];
  const float* wo1      = (const float*)d_in[22];
  const float* bo1      = (const float*)d_in[23];
  const float* wo2      = (const float*)d_in[24];
  const float* bo2      = (const float*)d_in[25];
  const float* wo3      = (const float*)d_in[26];
  const float* bo3      = (const float*)d_in[27];
  float* out = (float*)d_out;

  // workspace layout (~14.3 MB)
  float* a_glob    = (float*)d_ws;                   // MAXACT*128
  float* coef_glob = a_glob + MAXACT * 128;          // MAXACT*192
  float* acc_glob  = coef_glob + MAXACT * 192;       // MAXACT*544
  float* meta_f    = acc_glob + (size_t)MAXACT * ACCW;  // MAXACT*4
  float* vabs      = meta_f + MAXACT * 4;            // 64*80
  float* sfull     = vabs + NB * OD_;                // 512*80
  int* widx   = (int*)(sfull + NE_ * OD_);           // 8192
  int* active = widx + FLAT;                         // 4096
  int* meta_b = active + MAXACT;                     // 4096
  int* count  = meta_b + MAXACT;                     // 1

  k_init<<<32, 256, 0, stream>>>(vabs, widx, count);
  k_scatter<<<16, 256, 0, stream>>>(att_dst, widx);
  k_build<<<32, 256, 0, stream>>>(widx, active, count);
  k_node<<<MAXACT, 128, 0, stream>>>(count, active, widx, att_dist, att_vec, z, w_zemb,
                                     abs_idx, w1_rad, b1_rad, h, wg1, bg1, wg2, bg2,
                                     h_full, a_glob, coef_glob, meta_f, meta_b);
  k_rgemm<<<dim3(18, 64), 256, 0, stream>>>(count, a_glob, coef_glob, w2_rad, b2_rad,
                                            acc_glob);
  k_combine<<<1536, 256, 0, stream>>>(count, acc_glob, meta_f, meta_b, vabs);
  k_scales<<<512, 128, 0, stream>>>(e_feat, we1, be1, we2, be2, sfull);
  k_head<<<1024, 256, 0, stream>>>(vabs, sfull, wo1, bo1, wo2, bo2, wo3, bo3, out);
}

// Round 4
// 375.403 us; speedup vs baseline: 1.9044x; 1.0032x over previous
//
#include <hip/hip_runtime.h>
#include <math.h>

#define FLAT   8192
#define NB     64
#define OD_    80
#define NE_    512
#define EATT_  4096
#define MAXACT 4096
// per-node partial slot layout in acc_glob (544 floats/node):
//   chunks 0..11 (A,B): base c*32, 32 slots  -> out_s contributions
//   chunks 12..15 (C) : base 384+(c-12)*16   -> q (scalar coeff for yv)
//   chunks 16..17 (D) : base 448+(c-16)*48, layout comp*16+o -> out_v direct
#define ACCW 544

__device__ __forceinline__ float silu_f(float x) { return x / (1.f + __expf(-x)); }
__device__ __forceinline__ float sigm_f(float x) { return 1.f / (1.f + __expf(-x)); }

// ---------------- init ----------------
__global__ void k_init(float* vabs, int* widx, int* count) {
  int t = blockIdx.x * 256 + threadIdx.x;
  if (t < FLAT) widx[t] = -1;
  if (t < NB * OD_) vabs[t] = 0.f;
  if (t == 0) *count = 0;
}

// ---------------- scatter: last-write-wins == max edge index ----------------
__global__ void k_scatter(const int* __restrict__ att_dst, int* widx) {
  int i = blockIdx.x * 256 + threadIdx.x;
  if (i < EATT_) atomicMax(&widx[att_dst[i]], i);
}

// ---------------- compact active-node list ----------------
__global__ void k_build(const int* __restrict__ widx, int* active, int* count) {
  int j = blockIdx.x * 256 + threadIdx.x;
  if (j < FLAT && widx[j] >= 0) {
    int p = atomicAdd(count, 1);
    active[p] = j;
  }
}

// ---------------- per active node: rbf, hidden a(128), gate, env, coefs ----------------
__global__ void k_node(const int* __restrict__ count, const int* __restrict__ active,
                       const int* __restrict__ widx,
                       const float* __restrict__ att_dist, const float* __restrict__ att_vec,
                       const int* __restrict__ z, const float* __restrict__ w_zemb,
                       const int* __restrict__ abs_idx,
                       const float* __restrict__ w1_rad, const float* __restrict__ b1_rad,
                       const float* __restrict__ h,
                       const float* __restrict__ wg1, const float* __restrict__ bg1,
                       const float* __restrict__ wg2, const float* __restrict__ bg2,
                       const float* __restrict__ h_full,
                       float* a_glob, float* coef_glob, float* meta_f, int* meta_b) {
  int pos = blockIdx.x;
  if (pos >= *count) return;
  int t = threadIdx.x;  // 128 threads
  __shared__ float win[49];
  __shared__ float yv_s[3];
  __shared__ float red[128];
  __shared__ float sh_d;

  int j = active[pos];
  int b = j >> 7;
  int n = j & 127;
  int e = widx[j];

  if (t == 0) {
    float d = att_dist[e];
    sh_d = d;
    float eps = fmaxf(d, 1e-8f);
    const float s3 = 1.7320508075688772f;
    yv_s[0] = s3 * att_vec[e * 3 + 0] / eps;
    yv_s[1] = s3 * att_vec[e * 3 + 1] / eps;
    yv_s[2] = s3 * att_vec[e * 3 + 2] / eps;
  }
  int nabs = abs_idx[b];
  float isab = (n == nabs) ? 1.f : 0.f;
  if (t < 32) win[t] = w_zemb[z[j] * 32 + t];
  if (t == 32) win[32] = isab;
  if (t >= 33 && t < 49) {
    int k = t - 33;
    float d = att_dist[e];
    float x = (d - (float)k * (1.f / 3.f)) * 3.f;  // width = CUTOFF/(RBF-1) = 1/3
    win[t] = __expf(-0.5f * x * x);
  }
  __syncthreads();

  // hidden a = silu(win @ w1_rad + b1_rad)   (49 -> 128)
  {
    float s = b1_rad[t];
    for (int k = 0; k < 49; ++k) s = fmaf(win[k], w1_rad[k * 128 + t], s);
    a_glob[pos * 128 + t] = silu_f(s);
  }

  // gate MLP hidden (273 -> 128)
  {
    float g = bg1[t];
    const float* habs = h + (size_t)(b * 128 + nabs) * 128;
    const float* hn   = h + (size_t)j * 128;
    for (int c = 0; c < 128; ++c) g = fmaf(habs[c], wg1[c * 128 + t], g);
    for (int c = 0; c < 128; ++c) g = fmaf(hn[c],   wg1[(128 + c) * 128 + t], g);
    for (int k = 0; k < 16; ++k)  g = fmaf(win[33 + k], wg1[(256 + k) * 128 + t], g);
    g = fmaf(isab, wg1[272 * 128 + t], g);
    red[t] = silu_f(g) * wg2[t];
  }
  __syncthreads();

  // per-node contraction coefficients: [s1(64), p*inv_s3(32), v1(96)]
  const float* hf = h_full + (size_t)j * 160;
  if (t < 64) coef_glob[pos * 192 + t] = hf[t];
  if (t >= 64 && t < 96) {
    int i = t - 64;
    float pv = hf[64 + i * 3 + 0] * yv_s[0] + hf[64 + i * 3 + 1] * yv_s[1] +
               hf[64 + i * 3 + 2] * yv_s[2];
    coef_glob[pos * 192 + t] = pv * 0.5773502691896258f;
  }
  if (t < 96) coef_glob[pos * 192 + 96 + t] = hf[64 + t];

  if (t == 0) {
    float tot = 0.f;
    for (int k = 0; k < 128; ++k) tot += red[k];
    tot += bg2[0];
    float gate = sigm_f(tot);
    float d = sh_d;
    float env = (d < 5.f) ? 0.5f * (__cosf(3.14159265358979323846f * d * 0.2f) + 1.f) : 0.f;
    meta_f[pos * 4 + 0] = yv_s[0];
    meta_f[pos * 4 + 1] = yv_s[1];
    meta_f[pos * 4 + 2] = yv_s[2];
    meta_f[pos * 4 + 3] = gate * env;
    meta_b[pos] = b;
  }
}

// ---------------- radial GEMM + fused contraction (register-tiled) ----------------
// grid (18 col-chunks x 64 node-tiles). Block: 64 nodes x 256 cols, K=128.
// Thread: 4 nodes (ty) x 16 cols (tx), all compile-time indices.
// Round-3 lesson: holding a second 64-float vred[][] alongside acc[][] spilled
// (VGPR capped at 84, ~19 MB scratch writes). Epilogue is now STREAMING: one
// (j,i) element at a time -> shfl_xor reduce -> immediate predicated scalar
// store. Peak live set = acc(64) + cf(<=12) + temps.
__global__ __launch_bounds__(256, 3) void k_rgemm(const int* __restrict__ count,
                                                  const float* __restrict__ a_glob,
                                                  const float* __restrict__ coef_glob,
                                                  const float* __restrict__ w2,
                                                  const float* __restrict__ b2,
                                                  float* __restrict__ acc_glob) {
  int c = blockIdx.x;          // 0..17
  int nbase = blockIdx.y * 64;
  if (nbase >= *count) return;
  int t = threadIdx.x;
  int tx = t & 15, ty = t >> 4;

  __shared__ float a_s[64 * 132];   // stride 132: 16B-aligned, at most 2-way bank alias

  // stage a (coalesced float4)
  {
    const float4* ag = (const float4*)(a_glob + (size_t)nbase * 128);
#pragma unroll
    for (int it = 0; it < 8; ++it) {
      int f4 = t + it * 256;          // 0..2047
      int r = f4 >> 5, k4 = f4 & 31;
      *(float4*)&a_s[r * 132 + k4 * 4] = ag[f4];
    }
  }
  __syncthreads();

  int col0 = c * 256 + tx * 16;
  const float* wp = w2 + col0;
  int n0 = ty * 4;

  float acc[4][16];
#pragma unroll
  for (int i = 0; i < 4; ++i)
#pragma unroll
    for (int j = 0; j < 16; ++j) acc[i][j] = 0.f;

  for (int k4 = 0; k4 < 32; ++k4) {
    float4 av[4];
#pragma unroll
    for (int i = 0; i < 4; ++i)
      av[i] = *(const float4*)&a_s[(n0 + i) * 132 + k4 * 4];
#pragma unroll
    for (int kk = 0; kk < 4; ++kk) {
      const float* wrow = wp + (size_t)(k4 * 4 + kk) * 4608;
      float4 w0 = *(const float4*)(wrow + 0);
      float4 w1 = *(const float4*)(wrow + 4);
      float4 w2v = *(const float4*)(wrow + 8);
      float4 w3 = *(const float4*)(wrow + 12);
#pragma unroll
      for (int i = 0; i < 4; ++i) {
        float a = (kk == 0) ? av[i].x : (kk == 1) ? av[i].y : (kk == 2) ? av[i].z : av[i].w;
        acc[i][0]  = fmaf(a, w0.x,  acc[i][0]);
        acc[i][1]  = fmaf(a, w0.y,  acc[i][1]);
        acc[i][2]  = fmaf(a, w0.z,  acc[i][2]);
        acc[i][3]  = fmaf(a, w0.w,  acc[i][3]);
        acc[i][4]  = fmaf(a, w1.x,  acc[i][4]);
        acc[i][5]  = fmaf(a, w1.y,  acc[i][5]);
        acc[i][6]  = fmaf(a, w1.z,  acc[i][6]);
        acc[i][7]  = fmaf(a, w1.w,  acc[i][7]);
        acc[i][8]  = fmaf(a, w2v.x, acc[i][8]);
        acc[i][9]  = fmaf(a, w2v.y, acc[i][9]);
        acc[i][10] = fmaf(a, w2v.z, acc[i][10]);
        acc[i][11] = fmaf(a, w2v.w, acc[i][11]);
        acc[i][12] = fmaf(a, w3.x,  acc[i][12]);
        acc[i][13] = fmaf(a, w3.y,  acc[i][13]);
        acc[i][14] = fmaf(a, w3.z,  acc[i][14]);
        acc[i][15] = fmaf(a, w3.w,  acc[i][15]);
      }
    }
  }

  // + bias (tpw = a@w2 + b2)
  {
    const float* bp = b2 + col0;
    float4 b0 = *(const float4*)(bp + 0);
    float4 b1 = *(const float4*)(bp + 4);
    float4 b2v = *(const float4*)(bp + 8);
    float4 b3 = *(const float4*)(bp + 12);
#pragma unroll
    for (int i = 0; i < 4; ++i) {
      acc[i][0] += b0.x;  acc[i][1] += b0.y;  acc[i][2] += b0.z;  acc[i][3] += b0.w;
      acc[i][4] += b1.x;  acc[i][5] += b1.y;  acc[i][6] += b1.z;  acc[i][7] += b1.w;
      acc[i][8] += b2v.x; acc[i][9] += b2v.y; acc[i][10] += b2v.z; acc[i][11] += b2v.w;
      acc[i][12] += b3.x; acc[i][13] += b3.y; acc[i][14] += b3.z; acc[i][15] += b3.w;
    }
  }

  if (c < 12) {
    // A/B: col rel = i_loc*32 + o, i_loc = tx>>1, o = (tx&1)*16 + j.
    // coef index = c*8 + i_loc (A: s1 0..63; B: 64+(c-8)*8+i_loc == c*8+i_loc).
    int i_loc = tx >> 1;
    int coff = c * 8 + i_loc;
    int jsel = tx >> 1;          // this lane stores j = jsel and jsel+8
    int oo = (tx & 1) * 16;
    float cf[4];
#pragma unroll
    for (int i = 0; i < 4; ++i)
      cf[i] = coef_glob[(size_t)(nbase + n0 + i) * 192 + coff];
#pragma unroll
    for (int j = 0; j < 16; ++j) {
#pragma unroll
      for (int i = 0; i < 4; ++i) {
        float v = acc[i][j] * cf[i];
        v += __shfl_xor(v, 2);
        v += __shfl_xor(v, 4);
        v += __shfl_xor(v, 8);
        if ((j & 7) == jsel)
          acc_glob[(size_t)(nbase + n0 + i) * ACCW + c * 32 + oo + j] = v;
      }
    }
  } else if (c < 16) {
    // C: col rel = i_loc*16 + o, i_loc = tx, o = j. coef = s1[(c-12)*16+tx].
    int coff = (c - 12) * 16 + tx;
    float cf[4];
#pragma unroll
    for (int i = 0; i < 4; ++i)
      cf[i] = coef_glob[(size_t)(nbase + n0 + i) * 192 + coff];
#pragma unroll
    for (int j = 0; j < 16; ++j) {
#pragma unroll
      for (int i = 0; i < 4; ++i) {
        float v = acc[i][j] * cf[i];
        v += __shfl_xor(v, 1);
        v += __shfl_xor(v, 2);
        v += __shfl_xor(v, 4);
        v += __shfl_xor(v, 8);
        if (j == tx)
          acc_glob[(size_t)(nbase + n0 + i) * ACCW + 384 + (c - 12) * 16 + j] = v;
      }
    }
  } else {
    // D: col rel = i_loc*16 + o, i_loc = tx, o = j. v1 3-vector coefs.
    // Partial layout per chunk: comp*16 + o.
    int ibase = (c - 16) * 16 + tx;
    float c0[4], c1[4], c2[4];
#pragma unroll
    for (int i = 0; i < 4; ++i) {
      size_t cb = (size_t)(nbase + n0 + i) * 192 + 96 + (size_t)ibase * 3;
      c0[i] = coef_glob[cb + 0];
      c1[i] = coef_glob[cb + 1];
      c2[i] = coef_glob[cb + 2];
    }
#pragma unroll
    for (int comp = 0; comp < 3; ++comp) {
#pragma unroll
      for (int j = 0; j < 16; ++j) {
#pragma unroll
        for (int i = 0; i < 4; ++i) {
          float cc = (comp == 0) ? c0[i] : (comp == 1) ? c1[i] : c2[i];
          float v = acc[i][j] * cc;
          v += __shfl_xor(v, 1);
          v += __shfl_xor(v, 2);
          v += __shfl_xor(v, 4);
          v += __shfl_xor(v, 8);
          if (j == tx)
            acc_glob[(size_t)(nbase + n0 + i) * ACCW + 448 + (c - 16) * 48 + comp * 16 + j] = v;
        }
      }
    }
  }
}

// ---------------- reduce 544 partials/node -> v_abs[b][80] ----------------
__global__ void k_combine(const int* __restrict__ count, const float* __restrict__ acc_glob,
                          const float* __restrict__ meta_f, const int* __restrict__ meta_b,
                          float* vabs) {
  int g = blockIdx.x * 256 + threadIdx.x;
  int pos = g / 96, slot = g - pos * 96;
  if (pos >= *count) return;
  const float* acc = acc_glob + (size_t)pos * ACCW;
  float sc = meta_f[pos * 4 + 3] * 0.10206207261596577f;  // gate*env / sqrt(96)
  float* vb = vabs + meta_b[pos] * 80;
  if (slot < 32) {
    float s = 0.f;
#pragma unroll
    for (int cc = 0; cc < 12; ++cc) s += acc[cc * 32 + slot];
    atomicAdd(&vb[slot], s * sc);
  } else if (slot < 48) {
    int o = slot - 32;
    float q = acc[384 + o] + acc[384 + 16 + o] + acc[384 + 32 + o] + acc[384 + 48 + o];
    q *= sc;
    atomicAdd(&vb[32 + o * 3 + 0], q * meta_f[pos * 4 + 0]);
    atomicAdd(&vb[32 + o * 3 + 1], q * meta_f[pos * 4 + 1]);
    atomicAdd(&vb[32 + o * 3 + 2], q * meta_f[pos * 4 + 2]);
  } else {
    int s2 = slot - 48;         // s2 = o*3 + comp in output layout
    int o = s2 / 3, comp = s2 - o * 3;
    float dsum = acc[448 + comp * 16 + o] + acc[496 + comp * 16 + o];
    atomicAdd(&vb[32 + s2], dsum * sc);
  }
}

// ---------------- edge-feature scales -> scale_full[512][80] ----------------
__global__ void k_scales(const float* __restrict__ e_feat,
                         const float* __restrict__ we1, const float* __restrict__ be1,
                         const float* __restrict__ we2, const float* __restrict__ be2,
                         float* sfull) {
  int row = blockIdx.x;  // 512
  int t = threadIdx.x;   // 128
  __shared__ float hid[128];
  const float* ef = e_feat + row * 16;
  float s = be1[t];
  for (int k = 0; k < 16; ++k) s = fmaf(ef[k], we1[k * 128 + t], s);
  hid[t] = silu_f(s);
  __syncthreads();
  if (t < 48) {
    float o = be2[t];
    for (int k = 0; k < 128; ++k) o = fmaf(hid[k], we2[k * 48 + t], o);
    if (t < 32) sfull[row * 80 + t] = o;
    else {
      int oo = t - 32;
      sfull[row * 80 + 32 + oo * 3 + 0] = o;
      sfull[row * 80 + 32 + oo * 3 + 1] = o;
      sfull[row * 80 + 32 + oo * 3 + 2] = o;
    }
  }
}

// ---------------- head MLP: 32 rows/block, transposed LDS activations ----------------
__global__ __launch_bounds__(256) void k_head(const float* __restrict__ vabs,
                                              const float* __restrict__ sfull,
                                              const float* __restrict__ wo1, const float* __restrict__ bo1,
                                              const float* __restrict__ wo2, const float* __restrict__ bo2,
                                              const float* __restrict__ wo3, const float* __restrict__ bo3,
                                              float* __restrict__ out) {
  int blk = blockIdx.x;  // 1024 = 64 b x 16 e-tiles
  int b = blk >> 4;
  int e0 = (blk & 15) * 32;
  int t = threadIdx.x;

  __shared__ float va[80];
  __shared__ float smem[2592 + 4608 + 4608];  // sfl | x1_t | x2_t(alias inv_t)
  float* sfl  = smem;            // [32][81]
  float* x1t  = smem + 2592;     // [128][36]
  float* x2t  = smem + 7200;     // [128][36]
  float* invt = x2t;             // [48][36], dead before x2t written

  if (t < 80) va[t] = vabs[b * 80 + t];
  for (int idx = t; idx < 32 * 80; idx += 256) {
    int r = idx / 80, cc = idx - r * 80;
    sfl[r * 81 + cc] = sfull[e0 * 80 + idx];
  }
  __syncthreads();

  // inv (transposed [c][r], stride 36)
  for (int idx = t; idx < 48 * 32; idx += 256) {
    int cd = idx >> 5, r = idx & 31;
    float v;
    if (cd < 32) v = va[cd] * sfl[r * 81 + cd];
    else {
      int base = 32 + (cd - 32) * 3;
      float m0 = va[base + 0] * sfl[r * 81 + base + 0];
      float m1 = va[base + 1] * sfl[r * 81 + base + 1];
      float m2 = va[base + 2] * sfl[r * 81 + base + 2];
      v = sqrtf(m0 * m0 + m1 * m1 + m2 * m2 + 1e-12f);
    }
    invt[cd * 36 + r] = v;
  }
  __syncthreads();

  // L1: 48 -> 128, thread = (col, half-rows), 16 rows in registers
  {
    int col = t & 127, r0 = (t >> 7) * 16;
    float a[16];
    float bb = bo1[col];
#pragma unroll
    for (int r = 0; r < 16; ++r) a[r] = bb;
    for (int k = 0; k < 48; ++k) {
      float w = wo1[k * 128 + col];
      const float* xp = &invt[k * 36 + r0];
      float4 x0 = *(const float4*)(xp + 0);
      float4 x1 = *(const float4*)(xp + 4);
      float4 x2 = *(const float4*)(xp + 8);
      float4 x3 = *(const float4*)(xp + 12);
      float xs[16] = {x0.x, x0.y, x0.z, x0.w, x1.x, x1.y, x1.z, x1.w,
                      x2.x, x2.y, x2.z, x2.w, x3.x, x3.y, x3.z, x3.w};
#pragma unroll
      for (int r = 0; r < 16; ++r) a[r] = fmaf(xs[r], w, a[r]);
    }
#pragma unroll
    for (int r = 0; r < 16; ++r) x1t[col * 36 + r0 + r] = silu_f(a[r]);
  }
  __syncthreads();

  // L2: 128 -> 128
  {
    int col = t & 127, r0 = (t >> 7) * 16;
    float a[16];
    float bb = bo2[col];
#pragma unroll
    for (int r = 0; r < 16; ++r) a[r] = bb;
    for (int k = 0; k < 128; ++k) {
      float w = wo2[k * 128 + col];
      const float* xp = &x1t[k * 36 + r0];
      float4 x0 = *(const float4*)(xp + 0);
      float4 x1 = *(const float4*)(xp + 4);
      float4 x2 = *(const float4*)(xp + 8);
      float4 x3 = *(const float4*)(xp + 12);
      float xs[16] = {x0.x, x0.y, x0.z, x0.w, x1.x, x1.y, x1.z, x1.w,
                      x2.x, x2.y, x2.z, x2.w, x3.x, x3.y, x3.z, x3.w};
#pragma unroll
      for (int r = 0; r < 16; ++r) a[r] = fmaf(xs[r], w, a[r]);
    }
#pragma unroll
    for (int r = 0; r < 16; ++r) x2t[col * 36 + r0 + r] = silu_f(a[r]);
  }
  __syncthreads();

  // L3: 128 -> 256, thread = col, all 32 rows in registers
  {
    int col = t;
    float a[32];
    float bb = bo3[col];
#pragma unroll
    for (int r = 0; r < 32; ++r) a[r] = bb;
    for (int k = 0; k < 128; ++k) {
      float w = wo3[k * 256 + col];
      const float* xp = &x2t[k * 36];
#pragma unroll
      for (int q = 0; q < 8; ++q) {
        float4 xv = *(const float4*)(xp + q * 4);
        a[q * 4 + 0] = fmaf(xv.x, w, a[q * 4 + 0]);
        a[q * 4 + 1] = fmaf(xv.y, w, a[q * 4 + 1]);
        a[q * 4 + 2] = fmaf(xv.z, w, a[q * 4 + 2]);
        a[q * 4 + 3] = fmaf(xv.w, w, a[q * 4 + 3]);
      }
    }
    float* op = out + ((size_t)(b * 512 + e0)) * 256 + col;
#pragma unroll
    for (int r = 0; r < 32; ++r) op[(size_t)r * 256] = a[r];
  }
}

extern "C" void kernel_launch(void* const* d_in, const int* in_sizes, int n_in,
                              void* d_out, int out_size, void* d_ws, size_t ws_size,
                              hipStream_t stream) {
  const float* h        = (const float*)d_in[0];
  const float* h_full   = (const float*)d_in[1];
  const int*   z        = (const int*)d_in[2];
  const float* e_feat   = (const float*)d_in[4];
  const int*   abs_idx  = (const int*)d_in[5];
  const int*   att_dst  = (const int*)d_in[6];
  const float* att_dist = (const float*)d_in[7];
  const float* att_vec  = (const float*)d_in[8];
  const float* w_zemb   = (const float*)d_in[9];
  const float* w1_rad   = (const float*)d_in[10];
  const float* b1_rad   = (const float*)d_in[11];
  const float* w2_rad   = (const float*)d_in[12];
  const float* b2_rad   = (const float*)d_in[13];
  const float* wg1      = (const float*)d_in[14];
  const float* bg1      = (const float*)d_in[15];
  const float* wg2      = (const float*)d_in[16];
  const float* bg2      = (const float*)d_in[17];
  const float* we1      = (const float*)d_in[18];
  const float* be1      = (const float*)d_in[19];
  const float* we2      = (const float*)d_in[20];
  const float* be2      = (const float*)d_in[21];
  const float* wo1      = (const float*)d_in[22];
  const float* bo1      = (const float*)d_in[23];
  const float* wo2      = (const float*)d_in[24];
  const float* bo2      = (const float*)d_in[25];
  const float* wo3      = (const float*)d_in[26];
  const float* bo3      = (const float*)d_in[27];
  float* out = (float*)d_out;

  // workspace layout (~14.3 MB)
  float* a_glob    = (float*)d_ws;                   // MAXACT*128
  float* coef_glob = a_glob + MAXACT * 128;          // MAXACT*192
  float* acc_glob  = coef_glob + MAXACT * 192;       // MAXACT*544
  float* meta_f    = acc_glob + (size_t)MAXACT * ACCW;  // MAXACT*4
  float* vabs      = meta_f + MAXACT * 4;            // 64*80
  float* sfull     = vabs + NB * OD_;                // 512*80
  int* widx   = (int*)(sfull + NE_ * OD_);           // 8192
  int* active = widx + FLAT;                         // 4096
  int* meta_b = active + MAXACT;                     // 4096
  int* count  = meta_b + MAXACT;                     // 1

  k_init<<<32, 256, 0, stream>>>(vabs, widx, count);
  k_scatter<<<16, 256, 0, stream>>>(att_dst, widx);
  k_build<<<32, 256, 0, stream>>>(widx, active, count);
  k_node<<<MAXACT, 128, 0, stream>>>(count, active, widx, att_dist, att_vec, z, w_zemb,
                                     abs_idx, w1_rad, b1_rad, h, wg1, bg1, wg2, bg2,
                                     h_full, a_glob, coef_glob, meta_f, meta_b);
  k_rgemm<<<dim3(18, 64), 256, 0, stream>>>(count, a_glob, coef_glob, w2_rad, b2_rad,
                                            acc_glob);
  k_combine<<<1536, 256, 0, stream>>>(count, acc_glob, meta_f, meta_b, vabs);
  k_scales<<<512, 128, 0, stream>>>(e_feat, we1, be1, we2, be2, sfull);
  k_head<<<1024, 256, 0, stream>>>(vabs, sfull, wo1, bo1, wo2, bo2, wo3, bo3, out);
}